// Round 21
// baseline (205.899 us; speedup 1.0000x reference)
//
#include <hip/hip_runtime.h>

#define EPSV 1e-5f

typedef __bf16 bf16x8 __attribute__((ext_vector_type(8)));
typedef float f32x4 __attribute__((ext_vector_type(4)));
typedef unsigned int u32x4 __attribute__((ext_vector_type(4)));
typedef unsigned short u16x4 __attribute__((ext_vector_type(4)));

__device__ __forceinline__ unsigned short f2bf(float f) {
  return __builtin_bit_cast(unsigned short, static_cast<__bf16>(f));
}

// conv1 patch swizzle (R17)
__device__ __forceinline__ int swzB(int P, int k) {
  return P * 128 + (((k ^ (P & 7) ^ ((P >> 2) & 7)) & 7) << 4);
}

constexpr int Himg = 112, Wimg = 112, HWp = Himg * Wimg;  // 12544

// ---------------------------------------------------------------------------
// prep_misc: pack weights + BN scale/shift for all three BNs.
//   prm: [0)=s1 [64)=h1 [128)=s2 [192)=h2 [256)=s0 [320)=h0
// ---------------------------------------------------------------------------
__global__ __launch_bounds__(256) void prep_misc(
    const float* __restrict__ w1, const float* __restrict__ w2,
    const float* __restrict__ g0, const float* __restrict__ b0,
    const float* __restrict__ m0, const float* __restrict__ v0,
    const float* __restrict__ g1, const float* __restrict__ b1,
    const float* __restrict__ m1, const float* __restrict__ v1,
    const float* __restrict__ g2, const float* __restrict__ b2,
    const float* __restrict__ m2, const float* __restrict__ v2,
    unsigned short* __restrict__ wt1, unsigned short* __restrict__ wt2,
    float* __restrict__ prm)
{
  int id = blockIdx.x * 256 + threadIdx.x;
  for (int i = id; i < 9 * 2 * 4 * 512; i += gridDim.x * 256) {
    int j   = i & 7;
    int l   = (i >> 3) & 63;
    int c   = (i >> 9) & 3;
    int ks  = (i >> 11) & 1;
    int tap = i >> 12;
    int co  = c * 16 + (l & 15);
    int ci  = ks * 32 + (l >> 4) * 8 + j;
    int kh  = tap / 3, kw = tap - kh * 3;
    int src = ((co * 64 + ci) * 3 + kh) * 3 + kw;
    wt1[i] = f2bf(w1[src]);
    wt2[i] = f2bf(w2[src]);
  }
  if (id < 64) {
    float s1 = g1[id] * rsqrtf(v1[id] + EPSV);
    prm[id]      = s1;
    prm[64 + id] = b1[id] - m1[id] * s1;
    float s2 = g2[id] * rsqrtf(v2[id] + EPSV);
    prm[128 + id] = s2;
    prm[192 + id] = b2[id] - m2[id] * s2;
    float s0 = g0[id] * rsqrtf(v0[id] + EPSV);
    prm[256 + id] = s0;
    prm[320 + id] = b0[id] - m0[id] * s0;
  }
}

// ---------------------------------------------------------------------------
// conv1k: R19 form (best known: ~93us). 2-row tiles, 6-slot ring, ONE
//   barrier/tile, dist-1 prefetch (rows r0+3,r0+4 loaded at tile start,
//   emitted to spare slots 4,5 at tile end). NO ping-pong, NO sched_barrier
//   (R20's dist-2 regressed conv1k 93->116: single-stream kernel didn't need
//   depth; VGPR 120 + pinned schedule hurt).
// ---------------------------------------------------------------------------
__global__ __launch_bounds__(448, 2) void conv1k(
    const float* __restrict__ xsrc,
    const unsigned short* __restrict__ wP,
    const float* __restrict__ scale, const float* __restrict__ shift,
    const float* __restrict__ aP,
    const float* __restrict__ bn0sc, const float* __restrict__ bn0sh,
    unsigned short* __restrict__ dstb)
{
  constexpr int RS   = 114 * 128;   // 14592
  constexpr int WOFF = 6 * RS;      // 87552
  __shared__ __align__(16) unsigned char lds[WOFF + 73728];  // 161280

  const int t = threadIdx.x;
  const int b = blockIdx.x;
  const int n = b >> 2, q = b & 3;
  const int qbase = q * 28;
  const size_t ibase = (size_t)n * HWp;
  const float* xn = xsrc + (size_t)n * 64 * HWp;

  const int wv = t >> 6, l = t & 63;
  const int lo = l & 15, grp = l >> 4;

  const int cs = t / 28, wb = t - cs * 28;
  const int w0s = wb * 4;
  float scv[4], shv[4];
#pragma unroll
  for (int cc = 0; cc < 4; ++cc) {
    scv[cc] = bn0sc[cs * 4 + cc];
    shv[cc] = bn0sh[cs * 4 + cc];
  }

  auto load_rowx = [&](int hh, f32x4 (&A)[2], f32x4 (&B)[2]) -> bool {
    bool valid = (unsigned)hh < 112u;
#pragma unroll
    for (int u = 0; u < 2; ++u) {
      f32x4 z = {0.f, 0.f, 0.f, 0.f};
      A[u] = z; B[u] = z;
      if (valid) {
        const int ca = cs * 4 + u * 2;
        A[u] = *reinterpret_cast<const f32x4*>(xn + (size_t)ca * HWp + hh * Wimg + w0s);
        B[u] = *reinterpret_cast<const f32x4*>(xn + (size_t)(ca + 1) * HWp + hh * Wimg + w0s);
      }
    }
    return valid;
  };
  auto emit_rowx = [&](int rbX, const f32x4 (&A)[2], const f32x4 (&B)[2], bool valid) {
#pragma unroll
    for (int u = 0; u < 2; ++u) {
      const int ca = cs * 4 + u * 2;
      const int kk = ca >> 3;
      const int off = (ca & 7) * 2;
#pragma unroll
      for (int j = 0; j < 4; ++j) {
        float fa = valid ? A[u][j] * scv[u * 2] + shv[u * 2] : 0.f;
        float fb = valid ? B[u][j] * scv[u * 2 + 1] + shv[u * 2 + 1] : 0.f;
        unsigned int pk = (unsigned int)f2bf(fa) | ((unsigned int)f2bf(fb) << 16);
        int P = w0s + j + 1;
        *reinterpret_cast<unsigned int*>(&lds[rbX + swzB(P, kk) + off]) = pk;
      }
    }
  };

  // weights full (once), linear region
#pragma unroll
  for (int it = 0; it < 11; ++it) {
    int idx = t + it * 448;
    if (it < 10 || idx < 4608) {
      u32x4 v = *reinterpret_cast<const u32x4*>(wP + idx * 8);
      *reinterpret_cast<u32x4*>(&lds[WOFF + idx * 16]) = v;
    }
  }
  // halo zero: wpad cols (P=0,113), 6 slots
  if (t < 96) {
    int r = t >> 4, P = ((t >> 3) & 1) ? 113 : 0, k = t & 7;
    u32x4 z = {0u, 0u, 0u, 0u};
    *reinterpret_cast<u32x4*>(&lds[r * RS + swzB(P, k)]) = z;
  }
  // rows qbase-1 .. qbase+2 -> slots 0..3
#pragma unroll
  for (int r = 0; r < 4; ++r) {
    f32x4 A[2], B[2];
    bool v = load_rowx(qbase - 1 + r, A, B);
    emit_rowx(r * RS, A, B, v);
  }
  __syncthreads();

  int rb0 = 0 * RS, rb1 = 1 * RS, rb2 = 2 * RS, rb3 = 3 * RS, rb4 = 4 * RS, rb5 = 5 * RS;

  for (int T = 0; T < 14; ++T) {
    const int r0 = qbase + T * 2;

    // prefetch rows r0+3, r0+4 into regs (dist-1)
    f32x4 pA[2][2], pB[2][2];
    bool pv[2];
    if (T < 13) {
#pragma unroll
      for (int rr = 0; rr < 2; ++rr)
        pv[rr] = load_rowx(r0 + 3 + rr, pA[rr], pB[rr]);
    }

    f32x4 acc[4][2];
#pragma unroll
    for (int c = 0; c < 4; ++c)
#pragma unroll
      for (int p = 0; p < 2; ++p) {
        f32x4 z = {0.f, 0.f, 0.f, 0.f};
        acc[c][p] = z;
      }

    // K-loop: 18 steps, reads slots 0..3 only
#pragma unroll
    for (int s = 0; s < 18; ++s) {
      const int tap = s >> 1, ks = s & 1;
      const int dh = tap / 3, dw = tap - dh * 3;
      bf16x8 wf[4], pf[2];
#pragma unroll
      for (int c = 0; c < 4; ++c)
        wf[c] = *reinterpret_cast<const bf16x8*>(&lds[WOFF + (s * 4 + c) * 1024 + l * 16]);
      const int Pr = wv * 16 + lo + dw;
      const int c8 = (ks << 2) | grp;
      const int pbyte = swzB(Pr, c8);
#pragma unroll
      for (int p = 0; p < 2; ++p) {
        const int rr = p + dh;             // 0..3
        const int rbr = (rr == 0) ? rb0 : (rr == 1) ? rb1 : (rr == 2) ? rb2 : rb3;
        pf[p] = *reinterpret_cast<const bf16x8*>(&lds[rbr + pbyte]);
      }
#pragma unroll
      for (int c = 0; c < 4; ++c)
#pragma unroll
        for (int p = 0; p < 2; ++p)
          acc[c][p] = __builtin_amdgcn_mfma_f32_16x16x32_bf16(wf[c], pf[p], acc[c][p], 0, 0, 0);
    }

    // epilogue: rows r0, r0+1 -> y1 bf16 NHWC
#pragma unroll
    for (int c = 0; c < 4; ++c) {
      const int co0 = c * 16 + grp * 4;
      float s_[4], h_[4], a_[4];
#pragma unroll
      for (int j = 0; j < 4; ++j) {
        s_[j] = scale[co0 + j];
        h_[j] = shift[co0 + j];
        a_[j] = aP[co0 + j];
      }
      const int w = wv * 16 + lo;
#pragma unroll
      for (int p = 0; p < 2; ++p) {
        const int hh = r0 + p;
        f32x4 v = acc[c][p];
        u16x4 u;
#pragma unroll
        for (int j = 0; j < 4; ++j) {
          float vv = v[j] * s_[j] + h_[j];
          vv = vv >= 0.f ? vv : vv * a_[j];
          u[j] = f2bf(vv);
        }
        *reinterpret_cast<u16x4*>(dstb + (ibase + hh * Wimg + w) * 64 + co0) = u;
      }
    }

    // emit to spare slots 4,5 (disjoint from read slots 0-3) + ONE barrier
    if (T < 13) {
      emit_rowx(rb4, pA[0], pB[0], pv[0]);
      emit_rowx(rb5, pA[1], pB[1], pv[1]);
      __syncthreads();
    }

    // rotate by 2: new(0..5) = old(2,3,4,5,0,1)
    int n0 = rb2, n1 = rb3, n2 = rb4, n3 = rb5, n4 = rb0, n5 = rb1;
    rb0 = n0; rb1 = n1; rb2 = n2; rb3 = n3; rb4 = n4; rb5 = n5;
  }
}

// ---------------------------------------------------------------------------
// conv2k: R20 form (AT streaming floor ~80us): 2-row tiles, 6-slot ring,
//   one barrier/tile, FULL resid prefetch, prefetch distance 2 on y1 staging.
// ---------------------------------------------------------------------------
__global__ __launch_bounds__(448, 2) void conv2k(
    const unsigned short* __restrict__ src,   // y1 bf16 NHWC
    const unsigned short* __restrict__ wP,
    const float* __restrict__ scale, const float* __restrict__ shift,
    const float* __restrict__ aP,
    float* __restrict__ dstf,
    const float* __restrict__ resid)
{
  constexpr int RS   = 114 * 128;   // 14592
  constexpr int WOFF = 6 * RS;      // 87552
  __shared__ __align__(16) unsigned char lds[WOFF + 73728];  // 161280

  const int t = threadIdx.x;
  const int b = blockIdx.x;
  const int n = b >> 2, q = b & 3;
  const int qbase = q * 28;
  const size_t ibase = (size_t)n * HWp;

  const int wv = t >> 6, l = t & 63;
  const int lo = l & 15, grp = l >> 4;

  auto load_y1row2 = [&](int hbase, u32x4 (&pr)[4]) {
#pragma unroll
    for (int it = 0; it < 4; ++it) {
      int j = it >> 1;
      int rem = t + (it & 1) * 448;
      int w = rem >> 3, k = rem & 7;
      int hh = hbase + j;
      u32x4 val = {0u, 0u, 0u, 0u};
      if ((unsigned)hh < 112u)
        val = *reinterpret_cast<const u32x4*>(src + (ibase + hh * Wimg + w) * 64 + k * 8);
      pr[it] = val;
    }
  };

#pragma unroll
  for (int it = 0; it < 11; ++it) {
    int idx = t + it * 448;
    if (it < 10 || idx < 4608) {
      u32x4 v = *reinterpret_cast<const u32x4*>(wP + idx * 8);
      *reinterpret_cast<u32x4*>(&lds[WOFF + idx * 16]) = v;
    }
  }
  // halo zero: 6 slots
  if (t < 96) {
    int r = t >> 4, P = ((t >> 3) & 1) ? 113 : 0, k = t & 7;
    u32x4 z = {0u, 0u, 0u, 0u};
    *reinterpret_cast<u32x4*>(&lds[r * RS + P * 128 + ((k ^ (P & 7)) << 4)]) = z;
  }
  // rows qbase-1 .. qbase+2 -> slots 0..3
#pragma unroll
  for (int it = 0; it < 8; ++it) {
    int r = it >> 1;
    int rem = t + (it & 1) * 448;
    int w = rem >> 3, k = rem & 7;
    int hh = qbase - 1 + r;
    u32x4 val = {0u, 0u, 0u, 0u};
    if ((unsigned)hh < 112u)
      val = *reinterpret_cast<const u32x4*>(src + (ibase + hh * Wimg + w) * 64 + k * 8);
    int P = w + 1;
    *reinterpret_cast<u32x4*>(&lds[r * RS + P * 128 + ((k ^ (P & 7)) << 4)]) = val;
  }
  // pregA: rows qbase+3, qbase+4
  u32x4 prgA[4];
  load_y1row2(qbase + 3, prgA);
  __syncthreads();

  int rb0 = 0 * RS, rb1 = 1 * RS, rb2 = 2 * RS, rb3 = 3 * RS, rb4 = 4 * RS, rb5 = 5 * RS;

  for (int T = 0; T < 14; ++T) {
    const int r0 = qbase + T * 2;

    // FULL resid prefetch (32 f32): drains under the K-loop
    float rres[4][2][4];
#pragma unroll
    for (int c = 0; c < 4; ++c)
#pragma unroll
      for (int p = 0; p < 2; ++p)
#pragma unroll
        for (int j = 0; j < 4; ++j) {
          size_t idx = ((size_t)(n * 64 + c * 16 + grp * 4 + j) * Himg + (r0 + p)) * Wimg
                       + wv * 16 + lo;
          rres[c][p][j] = resid[idx];
        }

    // issue pregB = rows r0+5, r0+6 (emit at end of T+1)
    u32x4 prgB[4];
    if (T < 12) load_y1row2(r0 + 5, prgB);
    __builtin_amdgcn_sched_barrier(0);

    f32x4 acc[4][2];
#pragma unroll
    for (int c = 0; c < 4; ++c)
#pragma unroll
      for (int p = 0; p < 2; ++p) {
        f32x4 z = {0.f, 0.f, 0.f, 0.f};
        acc[c][p] = z;
      }

#pragma unroll
    for (int s = 0; s < 18; ++s) {
      const int tap = s >> 1, ks = s & 1;
      const int dh = tap / 3, dw = tap - dh * 3;
      bf16x8 wf[4], pf[2];
#pragma unroll
      for (int c = 0; c < 4; ++c)
        wf[c] = *reinterpret_cast<const bf16x8*>(&lds[WOFF + (s * 4 + c) * 1024 + l * 16]);
      const int Pr = wv * 16 + lo + dw;
      const int c8 = (ks << 2) | grp;
      const int pbyte = Pr * 128 + ((c8 ^ (Pr & 7)) << 4);
#pragma unroll
      for (int p = 0; p < 2; ++p) {
        const int rr = p + dh;
        const int rbr = (rr == 0) ? rb0 : (rr == 1) ? rb1 : (rr == 2) ? rb2 : rb3;
        pf[p] = *reinterpret_cast<const bf16x8*>(&lds[rbr + pbyte]);
      }
#pragma unroll
      for (int c = 0; c < 4; ++c)
#pragma unroll
        for (int p = 0; p < 2; ++p)
          acc[c][p] = __builtin_amdgcn_mfma_f32_16x16x32_bf16(wf[c], pf[p], acc[c][p], 0, 0, 0);
    }

#pragma unroll
    for (int c = 0; c < 4; ++c) {
      const int co0 = c * 16 + grp * 4;
      float s_[4], h_[4], a_[4];
#pragma unroll
      for (int j = 0; j < 4; ++j) {
        s_[j] = scale[co0 + j];
        h_[j] = shift[co0 + j];
        a_[j] = aP[co0 + j];
      }
      const int w = wv * 16 + lo;
#pragma unroll
      for (int p = 0; p < 2; ++p) {
        const int hh = r0 + p;
        f32x4 v = acc[c][p];
#pragma unroll
        for (int j = 0; j < 4; ++j) {
          size_t idx = ((size_t)(n * 64 + co0 + j) * Himg + hh) * Wimg + w;
          float vv = v[j] * s_[j] + h_[j] + rres[c][p][j];
          vv = vv >= 0.f ? vv : vv * a_[j];
          dstf[idx] = vv;
        }
      }
    }

    // emit pregA (rows r0+3, r0+4) to spare slots 4,5 + ONE barrier
    if (T < 13) {
#pragma unroll
      for (int it = 0; it < 4; ++it) {
        int j = it >> 1;
        int rem = t + (it & 1) * 448;
        int w = rem >> 3, k = rem & 7;
        int P = w + 1;
        const int dst = (j == 0) ? rb4 : rb5;
        *reinterpret_cast<u32x4*>(&lds[dst + P * 128 + ((k ^ (P & 7)) << 4)]) = prgA[it];
      }
      __syncthreads();
    }

    // ping-pong preg sets
    if (T < 12) {
#pragma unroll
      for (int it = 0; it < 4; ++it) prgA[it] = prgB[it];
    }

    // rotate by 2: new(0..5) = old(2,3,4,5,0,1)
    int n0 = rb2, n1 = rb3, n2 = rb4, n3 = rb5, n4 = rb0, n5 = rb1;
    rb0 = n0; rb1 = n1; rb2 = n2; rb3 = n3; rb4 = n4; rb5 = n5;
  }
}

// ---------------------------------------------------------------------------
// scratch map:
//   d_ws [0 .. 102,760,448)     : y1 bf16 NHWC
//   d_ws [+0 .. +73,728)        : wt1 packed bf16
//   d_ws [+73,728 .. +147,456)  : wt2 packed bf16
//   d_ws [+147,456 .. +149,000) : prm f32 (384 floats)
// ---------------------------------------------------------------------------
extern "C" void kernel_launch(void* const* d_in, const int* in_sizes, int n_in,
                              void* d_out, int out_size, void* d_ws, size_t ws_size,
                              hipStream_t stream)
{
  const float* x  = (const float*)d_in[0];
  const float* w1 = (const float*)d_in[1];
  const float* w2 = (const float*)d_in[2];
  const float* g0 = (const float*)d_in[3];
  const float* b0 = (const float*)d_in[4];
  const float* m0 = (const float*)d_in[5];
  const float* v0 = (const float*)d_in[6];
  const float* g1 = (const float*)d_in[7];
  const float* b1 = (const float*)d_in[8];
  const float* m1 = (const float*)d_in[9];
  const float* v1 = (const float*)d_in[10];
  const float* g2 = (const float*)d_in[11];
  const float* b2 = (const float*)d_in[12];
  const float* m2 = (const float*)d_in[13];
  const float* v2 = (const float*)d_in[14];
  const float* a1 = (const float*)d_in[15];
  const float* a2 = (const float*)d_in[16];

  unsigned char* wsb = (unsigned char*)d_ws;
  unsigned short* y1  = (unsigned short*)wsb;
  unsigned short* wt1 = (unsigned short*)(wsb + 102760448);
  unsigned short* wt2 = (unsigned short*)(wsb + 102760448 + 73728);
  float* prm          = (float*)(wsb + 102760448 + 2 * 73728);

  prep_misc<<<16, 256, 0, stream>>>(w1, w2, g0, b0, m0, v0, g1, b1, m1, v1,
                                    g2, b2, m2, v2, wt1, wt2, prm);
  conv1k<<<256, 448, 0, stream>>>(x, wt1, prm, prm + 64, a1, prm + 256, prm + 320, y1);
  conv2k<<<256, 448, 0, stream>>>(y1, wt2, prm + 128, prm + 192, a2, (float*)d_out, x);
}

// Round 22
// 205.881 us; speedup vs baseline: 1.0001x; 1.0001x over previous
//
#include <hip/hip_runtime.h>

#define EPSV 1e-5f

typedef __bf16 bf16x8 __attribute__((ext_vector_type(8)));
typedef float f32x4 __attribute__((ext_vector_type(4)));
typedef unsigned int u32x4 __attribute__((ext_vector_type(4)));
typedef unsigned short u16x4 __attribute__((ext_vector_type(4)));

__device__ __forceinline__ unsigned short f2bf(float f) {
  return __builtin_bit_cast(unsigned short, static_cast<__bf16>(f));
}

// conv1 patch swizzle (R17)
__device__ __forceinline__ int swzB(int P, int k) {
  return P * 128 + (((k ^ (P & 7) ^ ((P >> 2) & 7)) & 7) << 4);
}

constexpr int Himg = 112, Wimg = 112, HWp = Himg * Wimg;  // 12544

// ---------------------------------------------------------------------------
// prep_misc: pack weights + BN scale/shift for all three BNs.
//   prm: [0)=s1 [64)=h1 [128)=s2 [192)=h2 [256)=s0 [320)=h0
// ---------------------------------------------------------------------------
__global__ __launch_bounds__(256) void prep_misc(
    const float* __restrict__ w1, const float* __restrict__ w2,
    const float* __restrict__ g0, const float* __restrict__ b0,
    const float* __restrict__ m0, const float* __restrict__ v0,
    const float* __restrict__ g1, const float* __restrict__ b1,
    const float* __restrict__ m1, const float* __restrict__ v1,
    const float* __restrict__ g2, const float* __restrict__ b2,
    const float* __restrict__ m2, const float* __restrict__ v2,
    unsigned short* __restrict__ wt1, unsigned short* __restrict__ wt2,
    float* __restrict__ prm)
{
  int id = blockIdx.x * 256 + threadIdx.x;
  for (int i = id; i < 9 * 2 * 4 * 512; i += gridDim.x * 256) {
    int j   = i & 7;
    int l   = (i >> 3) & 63;
    int c   = (i >> 9) & 3;
    int ks  = (i >> 11) & 1;
    int tap = i >> 12;
    int co  = c * 16 + (l & 15);
    int ci  = ks * 32 + (l >> 4) * 8 + j;
    int kh  = tap / 3, kw = tap - kh * 3;
    int src = ((co * 64 + ci) * 3 + kh) * 3 + kw;
    wt1[i] = f2bf(w1[src]);
    wt2[i] = f2bf(w2[src]);
  }
  if (id < 64) {
    float s1 = g1[id] * rsqrtf(v1[id] + EPSV);
    prm[id]      = s1;
    prm[64 + id] = b1[id] - m1[id] * s1;
    float s2 = g2[id] * rsqrtf(v2[id] + EPSV);
    prm[128 + id] = s2;
    prm[192 + id] = b2[id] - m2[id] * s2;
    float s0 = g0[id] * rsqrtf(v0[id] + EPSV);
    prm[256 + id] = s0;
    prm[320 + id] = b0[id] - m0[id] * s0;
  }
}

// ---------------------------------------------------------------------------
// conv1k: 2-row tiles, 6-slot ring, one barrier/tile, DIST-2 PREFETCH via
//   2-TILE LOOP UNROLL: two prefetch sets alternate structurally (tile T
//   loads one set, emits the other) — no sched_barrier pin, no reg copies
//   (R20's pinned+copied dist-2 regressed; R19's dist-1 left the emit
//   waiting on loads issued only one K-loop earlier).
// ---------------------------------------------------------------------------
__global__ __launch_bounds__(448, 2) void conv1k(
    const float* __restrict__ xsrc,
    const unsigned short* __restrict__ wP,
    const float* __restrict__ scale, const float* __restrict__ shift,
    const float* __restrict__ aP,
    const float* __restrict__ bn0sc, const float* __restrict__ bn0sh,
    unsigned short* __restrict__ dstb)
{
  constexpr int RS   = 114 * 128;   // 14592
  constexpr int WOFF = 6 * RS;      // 87552
  __shared__ __align__(16) unsigned char lds[WOFF + 73728];  // 161280

  const int t = threadIdx.x;
  const int b = blockIdx.x;
  const int n = b >> 2, q = b & 3;
  const int qbase = q * 28;
  const size_t ibase = (size_t)n * HWp;
  const float* xn = xsrc + (size_t)n * 64 * HWp;

  const int wv = t >> 6, l = t & 63;
  const int lo = l & 15, grp = l >> 4;

  const int cs = t / 28, wb = t - cs * 28;
  const int w0s = wb * 4;
  float scv[4], shv[4];
#pragma unroll
  for (int cc = 0; cc < 4; ++cc) {
    scv[cc] = bn0sc[cs * 4 + cc];
    shv[cc] = bn0sh[cs * 4 + cc];
  }

  auto load_rowx = [&](int hh, f32x4 (&A)[2], f32x4 (&B)[2]) -> bool {
    bool valid = (unsigned)hh < 112u;
#pragma unroll
    for (int u = 0; u < 2; ++u) {
      f32x4 z = {0.f, 0.f, 0.f, 0.f};
      A[u] = z; B[u] = z;
      if (valid) {
        const int ca = cs * 4 + u * 2;
        A[u] = *reinterpret_cast<const f32x4*>(xn + (size_t)ca * HWp + hh * Wimg + w0s);
        B[u] = *reinterpret_cast<const f32x4*>(xn + (size_t)(ca + 1) * HWp + hh * Wimg + w0s);
      }
    }
    return valid;
  };
  auto emit_rowx = [&](int rbX, const f32x4 (&A)[2], const f32x4 (&B)[2], bool valid) {
#pragma unroll
    for (int u = 0; u < 2; ++u) {
      const int ca = cs * 4 + u * 2;
      const int kk = ca >> 3;
      const int off = (ca & 7) * 2;
#pragma unroll
      for (int j = 0; j < 4; ++j) {
        float fa = valid ? A[u][j] * scv[u * 2] + shv[u * 2] : 0.f;
        float fb = valid ? B[u][j] * scv[u * 2 + 1] + shv[u * 2 + 1] : 0.f;
        unsigned int pk = (unsigned int)f2bf(fa) | ((unsigned int)f2bf(fb) << 16);
        int P = w0s + j + 1;
        *reinterpret_cast<unsigned int*>(&lds[rbX + swzB(P, kk) + off]) = pk;
      }
    }
  };

  // weights full (once), linear region
#pragma unroll
  for (int it = 0; it < 11; ++it) {
    int idx = t + it * 448;
    if (it < 10 || idx < 4608) {
      u32x4 v = *reinterpret_cast<const u32x4*>(wP + idx * 8);
      *reinterpret_cast<u32x4*>(&lds[WOFF + idx * 16]) = v;
    }
  }
  // halo zero: wpad cols (P=0,113), 6 slots
  if (t < 96) {
    int r = t >> 4, P = ((t >> 3) & 1) ? 113 : 0, k = t & 7;
    u32x4 z = {0u, 0u, 0u, 0u};
    *reinterpret_cast<u32x4*>(&lds[r * RS + swzB(P, k)]) = z;
  }
  // rows qbase-1 .. qbase+2 -> slots 0..3
#pragma unroll
  for (int r = 0; r < 4; ++r) {
    f32x4 A[2], B[2];
    bool v = load_rowx(qbase - 1 + r, A, B);
    emit_rowx(r * RS, A, B, v);
  }

  int rb0 = 0 * RS, rb1 = 1 * RS, rb2 = 2 * RS, rb3 = 3 * RS, rb4 = 4 * RS, rb5 = 5 * RS;

  // two prefetch sets (alternate per tile; no copies)
  struct Pref { f32x4 A[2][2]; f32x4 B[2][2]; bool v[2]; };
  Pref sa, sb;

  auto load_set = [&](int hbase, Pref& s) {
#pragma unroll
    for (int rr = 0; rr < 2; ++rr)
      s.v[rr] = load_rowx(hbase + rr, s.A[rr], s.B[rr]);
  };

  // prologue: sa = rows qbase+3, qbase+4 (tile 0's emit)
  load_set(qbase + 3, sa);
  __syncthreads();

  auto do_tile = [&](int T, Pref& ld, Pref& em) {
    const int r0 = qbase + T * 2;

    // issue loads for tile T+1's emit (rows r0+5, r0+6) — 2 tile-periods slack
    if (T < 12) load_set(r0 + 5, ld);

    f32x4 acc[4][2];
#pragma unroll
    for (int c = 0; c < 4; ++c)
#pragma unroll
      for (int p = 0; p < 2; ++p) {
        f32x4 z = {0.f, 0.f, 0.f, 0.f};
        acc[c][p] = z;
      }

    // K-loop: 18 steps, reads slots 0..3 only
#pragma unroll
    for (int s = 0; s < 18; ++s) {
      const int tap = s >> 1, ks = s & 1;
      const int dh = tap / 3, dw = tap - dh * 3;
      bf16x8 wf[4], pf[2];
#pragma unroll
      for (int c = 0; c < 4; ++c)
        wf[c] = *reinterpret_cast<const bf16x8*>(&lds[WOFF + (s * 4 + c) * 1024 + l * 16]);
      const int Pr = wv * 16 + lo + dw;
      const int c8 = (ks << 2) | grp;
      const int pbyte = swzB(Pr, c8);
#pragma unroll
      for (int p = 0; p < 2; ++p) {
        const int rr = p + dh;             // 0..3
        const int rbr = (rr == 0) ? rb0 : (rr == 1) ? rb1 : (rr == 2) ? rb2 : rb3;
        pf[p] = *reinterpret_cast<const bf16x8*>(&lds[rbr + pbyte]);
      }
#pragma unroll
      for (int c = 0; c < 4; ++c)
#pragma unroll
        for (int p = 0; p < 2; ++p)
          acc[c][p] = __builtin_amdgcn_mfma_f32_16x16x32_bf16(wf[c], pf[p], acc[c][p], 0, 0, 0);
    }

    // epilogue: rows r0, r0+1 -> y1 bf16 NHWC
#pragma unroll
    for (int c = 0; c < 4; ++c) {
      const int co0 = c * 16 + grp * 4;
      float s_[4], h_[4], a_[4];
#pragma unroll
      for (int j = 0; j < 4; ++j) {
        s_[j] = scale[co0 + j];
        h_[j] = shift[co0 + j];
        a_[j] = aP[co0 + j];
      }
      const int w = wv * 16 + lo;
#pragma unroll
      for (int p = 0; p < 2; ++p) {
        const int hh = r0 + p;
        f32x4 v = acc[c][p];
        u16x4 u;
#pragma unroll
        for (int j = 0; j < 4; ++j) {
          float vv = v[j] * s_[j] + h_[j];
          vv = vv >= 0.f ? vv : vv * a_[j];
          u[j] = f2bf(vv);
        }
        *reinterpret_cast<u16x4*>(dstb + (ibase + hh * Wimg + w) * 64 + co0) = u;
      }
    }

    // emit (set loaded during tile T-1) to spare slots 4,5 + ONE barrier
    if (T < 13) {
      emit_rowx(rb4, em.A[0], em.B[0], em.v[0]);
      emit_rowx(rb5, em.A[1], em.B[1], em.v[1]);
      __syncthreads();
    }

    // rotate by 2: new(0..5) = old(2,3,4,5,0,1)
    int n0 = rb2, n1 = rb3, n2 = rb4, n3 = rb5, n4 = rb0, n5 = rb1;
    rb0 = n0; rb1 = n1; rb2 = n2; rb3 = n3; rb4 = n4; rb5 = n5;
  };

  for (int TT = 0; TT < 14; TT += 2) {
    do_tile(TT, sb, sa);       // loads sb (tile TT+1's emit), emits sa
    do_tile(TT + 1, sa, sb);   // loads sa (tile TT+2's emit), emits sb
  }
}

// ---------------------------------------------------------------------------
// conv2k: R20 form (AT streaming floor ~80us): 2-row tiles, 6-slot ring,
//   one barrier/tile, FULL resid prefetch, prefetch distance 2 on y1 staging.
// ---------------------------------------------------------------------------
__global__ __launch_bounds__(448, 2) void conv2k(
    const unsigned short* __restrict__ src,   // y1 bf16 NHWC
    const unsigned short* __restrict__ wP,
    const float* __restrict__ scale, const float* __restrict__ shift,
    const float* __restrict__ aP,
    float* __restrict__ dstf,
    const float* __restrict__ resid)
{
  constexpr int RS   = 114 * 128;   // 14592
  constexpr int WOFF = 6 * RS;      // 87552
  __shared__ __align__(16) unsigned char lds[WOFF + 73728];  // 161280

  const int t = threadIdx.x;
  const int b = blockIdx.x;
  const int n = b >> 2, q = b & 3;
  const int qbase = q * 28;
  const size_t ibase = (size_t)n * HWp;

  const int wv = t >> 6, l = t & 63;
  const int lo = l & 15, grp = l >> 4;

  auto load_y1row2 = [&](int hbase, u32x4 (&pr)[4]) {
#pragma unroll
    for (int it = 0; it < 4; ++it) {
      int j = it >> 1;
      int rem = t + (it & 1) * 448;
      int w = rem >> 3, k = rem & 7;
      int hh = hbase + j;
      u32x4 val = {0u, 0u, 0u, 0u};
      if ((unsigned)hh < 112u)
        val = *reinterpret_cast<const u32x4*>(src + (ibase + hh * Wimg + w) * 64 + k * 8);
      pr[it] = val;
    }
  };

#pragma unroll
  for (int it = 0; it < 11; ++it) {
    int idx = t + it * 448;
    if (it < 10 || idx < 4608) {
      u32x4 v = *reinterpret_cast<const u32x4*>(wP + idx * 8);
      *reinterpret_cast<u32x4*>(&lds[WOFF + idx * 16]) = v;
    }
  }
  // halo zero: 6 slots
  if (t < 96) {
    int r = t >> 4, P = ((t >> 3) & 1) ? 113 : 0, k = t & 7;
    u32x4 z = {0u, 0u, 0u, 0u};
    *reinterpret_cast<u32x4*>(&lds[r * RS + P * 128 + ((k ^ (P & 7)) << 4)]) = z;
  }
  // rows qbase-1 .. qbase+2 -> slots 0..3
#pragma unroll
  for (int it = 0; it < 8; ++it) {
    int r = it >> 1;
    int rem = t + (it & 1) * 448;
    int w = rem >> 3, k = rem & 7;
    int hh = qbase - 1 + r;
    u32x4 val = {0u, 0u, 0u, 0u};
    if ((unsigned)hh < 112u)
      val = *reinterpret_cast<const u32x4*>(src + (ibase + hh * Wimg + w) * 64 + k * 8);
    int P = w + 1;
    *reinterpret_cast<u32x4*>(&lds[r * RS + P * 128 + ((k ^ (P & 7)) << 4)]) = val;
  }
  // pregA: rows qbase+3, qbase+4
  u32x4 prgA[4];
  load_y1row2(qbase + 3, prgA);
  __syncthreads();

  int rb0 = 0 * RS, rb1 = 1 * RS, rb2 = 2 * RS, rb3 = 3 * RS, rb4 = 4 * RS, rb5 = 5 * RS;

  for (int T = 0; T < 14; ++T) {
    const int r0 = qbase + T * 2;

    // FULL resid prefetch (32 f32): drains under the K-loop
    float rres[4][2][4];
#pragma unroll
    for (int c = 0; c < 4; ++c)
#pragma unroll
      for (int p = 0; p < 2; ++p)
#pragma unroll
        for (int j = 0; j < 4; ++j) {
          size_t idx = ((size_t)(n * 64 + c * 16 + grp * 4 + j) * Himg + (r0 + p)) * Wimg
                       + wv * 16 + lo;
          rres[c][p][j] = resid[idx];
        }

    // issue pregB = rows r0+5, r0+6 (emit at end of T+1)
    u32x4 prgB[4];
    if (T < 12) load_y1row2(r0 + 5, prgB);
    __builtin_amdgcn_sched_barrier(0);

    f32x4 acc[4][2];
#pragma unroll
    for (int c = 0; c < 4; ++c)
#pragma unroll
      for (int p = 0; p < 2; ++p) {
        f32x4 z = {0.f, 0.f, 0.f, 0.f};
        acc[c][p] = z;
      }

#pragma unroll
    for (int s = 0; s < 18; ++s) {
      const int tap = s >> 1, ks = s & 1;
      const int dh = tap / 3, dw = tap - dh * 3;
      bf16x8 wf[4], pf[2];
#pragma unroll
      for (int c = 0; c < 4; ++c)
        wf[c] = *reinterpret_cast<const bf16x8*>(&lds[WOFF + (s * 4 + c) * 1024 + l * 16]);
      const int Pr = wv * 16 + lo + dw;
      const int c8 = (ks << 2) | grp;
      const int pbyte = Pr * 128 + ((c8 ^ (Pr & 7)) << 4);
#pragma unroll
      for (int p = 0; p < 2; ++p) {
        const int rr = p + dh;
        const int rbr = (rr == 0) ? rb0 : (rr == 1) ? rb1 : (rr == 2) ? rb2 : rb3;
        pf[p] = *reinterpret_cast<const bf16x8*>(&lds[rbr + pbyte]);
      }
#pragma unroll
      for (int c = 0; c < 4; ++c)
#pragma unroll
        for (int p = 0; p < 2; ++p)
          acc[c][p] = __builtin_amdgcn_mfma_f32_16x16x32_bf16(wf[c], pf[p], acc[c][p], 0, 0, 0);
    }

#pragma unroll
    for (int c = 0; c < 4; ++c) {
      const int co0 = c * 16 + grp * 4;
      float s_[4], h_[4], a_[4];
#pragma unroll
      for (int j = 0; j < 4; ++j) {
        s_[j] = scale[co0 + j];
        h_[j] = shift[co0 + j];
        a_[j] = aP[co0 + j];
      }
      const int w = wv * 16 + lo;
#pragma unroll
      for (int p = 0; p < 2; ++p) {
        const int hh = r0 + p;
        f32x4 v = acc[c][p];
#pragma unroll
        for (int j = 0; j < 4; ++j) {
          size_t idx = ((size_t)(n * 64 + co0 + j) * Himg + hh) * Wimg + w;
          float vv = v[j] * s_[j] + h_[j] + rres[c][p][j];
          vv = vv >= 0.f ? vv : vv * a_[j];
          dstf[idx] = vv;
        }
      }
    }

    // emit pregA (rows r0+3, r0+4) to spare slots 4,5 + ONE barrier
    if (T < 13) {
#pragma unroll
      for (int it = 0; it < 4; ++it) {
        int j = it >> 1;
        int rem = t + (it & 1) * 448;
        int w = rem >> 3, k = rem & 7;
        int P = w + 1;
        const int dst = (j == 0) ? rb4 : rb5;
        *reinterpret_cast<u32x4*>(&lds[dst + P * 128 + ((k ^ (P & 7)) << 4)]) = prgA[it];
      }
      __syncthreads();
    }

    // ping-pong preg sets
    if (T < 12) {
#pragma unroll
      for (int it = 0; it < 4; ++it) prgA[it] = prgB[it];
    }

    // rotate by 2: new(0..5) = old(2,3,4,5,0,1)
    int n0 = rb2, n1 = rb3, n2 = rb4, n3 = rb5, n4 = rb0, n5 = rb1;
    rb0 = n0; rb1 = n1; rb2 = n2; rb3 = n3; rb4 = n4; rb5 = n5;
  }
}

// ---------------------------------------------------------------------------
// scratch map:
//   d_ws [0 .. 102,760,448)     : y1 bf16 NHWC
//   d_ws [+0 .. +73,728)        : wt1 packed bf16
//   d_ws [+73,728 .. +147,456)  : wt2 packed bf16
//   d_ws [+147,456 .. +149,000) : prm f32 (384 floats)
// ---------------------------------------------------------------------------
extern "C" void kernel_launch(void* const* d_in, const int* in_sizes, int n_in,
                              void* d_out, int out_size, void* d_ws, size_t ws_size,
                              hipStream_t stream)
{
  const float* x  = (const float*)d_in[0];
  const float* w1 = (const float*)d_in[1];
  const float* w2 = (const float*)d_in[2];
  const float* g0 = (const float*)d_in[3];
  const float* b0 = (const float*)d_in[4];
  const float* m0 = (const float*)d_in[5];
  const float* v0 = (const float*)d_in[6];
  const float* g1 = (const float*)d_in[7];
  const float* b1 = (const float*)d_in[8];
  const float* m1 = (const float*)d_in[9];
  const float* v1 = (const float*)d_in[10];
  const float* g2 = (const float*)d_in[11];
  const float* b2 = (const float*)d_in[12];
  const float* m2 = (const float*)d_in[13];
  const float* v2 = (const float*)d_in[14];
  const float* a1 = (const float*)d_in[15];
  const float* a2 = (const float*)d_in[16];

  unsigned char* wsb = (unsigned char*)d_ws;
  unsigned short* y1  = (unsigned short*)wsb;
  unsigned short* wt1 = (unsigned short*)(wsb + 102760448);
  unsigned short* wt2 = (unsigned short*)(wsb + 102760448 + 73728);
  float* prm          = (float*)(wsb + 102760448 + 2 * 73728);

  prep_misc<<<16, 256, 0, stream>>>(w1, w2, g0, b0, m0, v0, g1, b1, m1, v1,
                                    g2, b2, m2, v2, wt1, wt2, prm);
  conv1k<<<256, 448, 0, stream>>>(x, wt1, prm, prm + 64, a1, prm + 256, prm + 320, y1);
  conv2k<<<256, 448, 0, stream>>>(y1, wt2, prm + 128, prm + 192, a2, (float*)d_out, x);
}